// Round 1
// baseline (226.281 us; speedup 1.0000x reference)
//
#include <hip/hip_runtime.h>
#include <hip/hip_bf16.h>

using f32x4  = __attribute__((ext_vector_type(4))) float;
using bf16x8 = __attribute__((ext_vector_type(8))) __bf16;

static __device__ __forceinline__ unsigned short f2bf(float f) {
    unsigned u = __builtin_bit_cast(unsigned, f);
    u += 0x7FFF + ((u >> 16) & 1);   // round-to-nearest-even
    return (unsigned short)(u >> 16);
}

// ---------------------------------------------------------------------------
// Kernel 1: Y = X @ W^T + bias, output bf16. M=4096, N=1024, K=1024.
// 128x128 tile, BK=32, 4 waves, each wave 64x64 via 4x4 mfma_f32_16x16x32_bf16.
// fp32 global -> reg -> bf16 LDS (rows padded to 40 bf16 = 80B: conflict-free).
// ---------------------------------------------------------------------------
#define BMg 128
#define BNg 128
#define BKg 32
#define LDSK 40

__global__ __launch_bounds__(256, 2) void proj_gemm(
    const float* __restrict__ X0, const float* __restrict__ X1, const float* __restrict__ X2,
    const float* __restrict__ W0, const float* __restrict__ W1, const float* __restrict__ W2,
    const float* __restrict__ b0, const float* __restrict__ b1, const float* __restrict__ b2,
    unsigned short* __restrict__ O0, unsigned short* __restrict__ O1, unsigned short* __restrict__ O2)
{
    const int N = 1024, K = 1024;
    const int which = blockIdx.y;
    const float* X = which == 0 ? X0 : (which == 1 ? X1 : X2);
    const float* W = which == 0 ? W0 : (which == 1 ? W1 : W2);
    const float* bias = which == 0 ? b0 : (which == 1 ? b1 : b2);
    unsigned short* O = which == 0 ? O0 : (which == 1 ? O1 : O2);

    const int bm = blockIdx.x >> 3;   // N/BNg = 8 tiles along N
    const int bn = blockIdx.x & 7;
    const int row0 = bm * BMg, col0 = bn * BNg;

    __shared__ __align__(16) unsigned short As[BMg * LDSK];
    __shared__ __align__(16) unsigned short Bs[BNg * LDSK];

    const int t = threadIdx.x;
    const int lane = t & 63;
    const int wave = t >> 6;
    const int wr = (wave >> 1) * 64, wc = (wave & 1) * 64;
    const int fr = lane & 15;   // fragment row (A/B) / col (C)
    const int fq = lane >> 4;   // 0..3

    f32x4 acc[4][4] = {};

    const int srow = t >> 3;        // 0..31
    const int scol = (t & 7) * 4;   // 0..28

    for (int k0 = 0; k0 < K; k0 += BKg) {
        __syncthreads();
        #pragma unroll
        for (int i = 0; i < 4; ++i) {
            const int r = srow + 32 * i;
            f32x4 xa = *(const f32x4*)(X + (size_t)(row0 + r) * K + k0 + scol);
            f32x4 xb = *(const f32x4*)(W + (size_t)(col0 + r) * K + k0 + scol);
            ushort4 ua, ub;
            ua.x = f2bf(xa.x); ua.y = f2bf(xa.y); ua.z = f2bf(xa.z); ua.w = f2bf(xa.w);
            ub.x = f2bf(xb.x); ub.y = f2bf(xb.y); ub.z = f2bf(xb.z); ub.w = f2bf(xb.w);
            *(ushort4*)(&As[r * LDSK + scol]) = ua;
            *(ushort4*)(&Bs[r * LDSK + scol]) = ub;
        }
        __syncthreads();

        bf16x8 af[4], bfr[4];
        #pragma unroll
        for (int m = 0; m < 4; ++m)
            af[m] = *(const bf16x8*)(&As[(wr + m * 16 + fr) * LDSK + fq * 8]);
        #pragma unroll
        for (int n = 0; n < 4; ++n)
            bfr[n] = *(const bf16x8*)(&Bs[(wc + n * 16 + fr) * LDSK + fq * 8]);
        #pragma unroll
        for (int m = 0; m < 4; ++m)
            #pragma unroll
            for (int n = 0; n < 4; ++n)
                acc[m][n] = __builtin_amdgcn_mfma_f32_16x16x32_bf16(af[m], bfr[n], acc[m][n], 0, 0, 0);
    }

    // epilogue: + bias, write bf16
    #pragma unroll
    for (int n = 0; n < 4; ++n) {
        const int col = col0 + wc + n * 16 + fr;
        const float bv = bias[col];
        #pragma unroll
        for (int m = 0; m < 4; ++m) {
            #pragma unroll
            for (int r = 0; r < 4; ++r) {
                const int row = row0 + wr + m * 16 + fq * 4 + r;
                O[(size_t)row * N + col] = f2bf(acc[m][n][r] + bv);
            }
        }
    }
}

// ---------------------------------------------------------------------------
// Kernel 2: causal flash attention per (b, h, 64-row q-block). 4 waves,
// wave owns 16 q-rows. K-tiles of 32. Online softmax in-register
// (shuffle-reduce over lane&15). P re-layout C->A via padded per-wave LDS.
// ---------------------------------------------------------------------------
#define QB 64
#define KB 32
#define KLD 72   // 64 + 8 pad (bf16)
#define VLD 40   // 32 + 8 pad
#define PLD 40

__global__ __launch_bounds__(256, 2) void attn_fwd(
    const unsigned short* __restrict__ Qw, const unsigned short* __restrict__ Kw,
    const unsigned short* __restrict__ Vw, const int* __restrict__ amask,
    float* __restrict__ out)
{
    const int S = 1024, Dm = 1024;
    const int qb = blockIdx.x, h = blockIdx.y, b = blockIdx.z;
    const int q0 = qb * QB;
    const int t = threadIdx.x, lane = t & 63, wave = t >> 6;
    const int fr = lane & 15, fq = lane >> 4;

    __shared__ __align__(16) unsigned short Ks[KB][KLD];
    __shared__ __align__(16) unsigned short Vts[64][VLD];
    __shared__ __align__(16) unsigned short Ps[4][16][PLD];

    // Q fragments (A-operand): row = lane&15, k = (lane>>4)*8+j (+32 per chunk)
    const int qrowA = q0 + wave * 16 + fr;
    const size_t qbase = ((size_t)(b * S + qrowA)) * Dm + h * 64;
    bf16x8 qf[2];
    qf[0] = *(const bf16x8*)(Qw + qbase + fq * 8);
    qf[1] = *(const bf16x8*)(Qw + qbase + 32 + fq * 8);

    f32x4 oacc[4] = {};
    float mrow[4], lrow[4];
    #pragma unroll
    for (int r = 0; r < 4; ++r) { mrow[r] = -3.0e38f; lrow[r] = 0.f; }

    const int nkt = (q0 + QB) / KB;
    const int srow = t >> 3;        // 0..31
    const int scol = (t & 7) * 8;   // 0..56

    for (int kt = 0; kt < nkt; ++kt) {
        const int k0 = kt * KB;
        __syncthreads();
        {   // stage K row-major, V transposed
            const size_t g = ((size_t)(b * S + k0 + srow)) * Dm + h * 64 + scol;
            *(bf16x8*)(&Ks[srow][scol]) = *(const bf16x8*)(Kw + g);
            bf16x8 v = *(const bf16x8*)(Vw + g);
            #pragma unroll
            for (int j = 0; j < 8; ++j)
                Vts[scol + j][srow] = ((const unsigned short*)&v)[j];
        }
        __syncthreads();

        // S = Q K^T  (two 16-col fragments, chained over dk)
        f32x4 sfr[2];
        #pragma unroll
        for (int nf = 0; nf < 2; ++nf) {
            bf16x8 kb0 = *(const bf16x8*)(&Ks[nf * 16 + fr][fq * 8]);
            bf16x8 kb1 = *(const bf16x8*)(&Ks[nf * 16 + fr][32 + fq * 8]);
            f32x4 z = {};
            z = __builtin_amdgcn_mfma_f32_16x16x32_bf16(qf[0], kb0, z, 0, 0, 0);
            z = __builtin_amdgcn_mfma_f32_16x16x32_bf16(qf[1], kb1, z, 0, 0, 0);
            sfr[nf] = z;
        }

        // scale + causal + att_mask
        float sv[2][4];
        #pragma unroll
        for (int nf = 0; nf < 2; ++nf) {
            const int kpos = k0 + nf * 16 + fr;
            const int mk = amask[b * S + kpos];
            #pragma unroll
            for (int r = 0; r < 4; ++r) {
                const int qrow = q0 + wave * 16 + fq * 4 + r;
                float v = sfr[nf][r] * 0.125f;
                if (kpos > qrow || mk == 0) v = -3.0e38f;
                sv[nf][r] = v;
            }
        }

        // row max over 32 cols (xor-reduce over lane&15)
        #pragma unroll
        for (int r = 0; r < 4; ++r) {
            float v = fmaxf(sv[0][r], sv[1][r]);
            v = fmaxf(v, __shfl_xor(v, 1));
            v = fmaxf(v, __shfl_xor(v, 2));
            v = fmaxf(v, __shfl_xor(v, 4));
            v = fmaxf(v, __shfl_xor(v, 8));
            const float mn = fmaxf(mrow[r], v);
            const float sc = __expf(mrow[r] - mn);
            mrow[r] = mn;
            lrow[r] *= sc;
            #pragma unroll
            for (int d = 0; d < 4; ++d) oacc[d][r] *= sc;
        }

        // p = exp(s - m), row-sum, write P (bf16) to per-wave LDS
        float rs[4] = {0.f, 0.f, 0.f, 0.f};
        #pragma unroll
        for (int nf = 0; nf < 2; ++nf) {
            #pragma unroll
            for (int r = 0; r < 4; ++r) {
                const float p = (sv[nf][r] < -1.0e37f) ? 0.f : __expf(sv[nf][r] - mrow[r]);
                rs[r] += p;
                Ps[wave][fq * 4 + r][nf * 16 + fr] = f2bf(p);
            }
        }
        #pragma unroll
        for (int r = 0; r < 4; ++r) {
            float v = rs[r];
            v += __shfl_xor(v, 1);
            v += __shfl_xor(v, 2);
            v += __shfl_xor(v, 4);
            v += __shfl_xor(v, 8);
            lrow[r] += v;
        }

        // O += P V
        bf16x8 pa = *(const bf16x8*)(&Ps[wave][fr][fq * 8]);
        #pragma unroll
        for (int d = 0; d < 4; ++d) {
            bf16x8 vb = *(const bf16x8*)(&Vts[d * 16 + fr][fq * 8]);
            oacc[d] = __builtin_amdgcn_mfma_f32_16x16x32_bf16(pa, vb, oacc[d], 0, 0, 0);
        }
    }

    // epilogue: divide by row sum, write fp32
    float inv[4];
    #pragma unroll
    for (int r = 0; r < 4; ++r) inv[r] = 1.0f / lrow[r];
    #pragma unroll
    for (int d = 0; d < 4; ++d) {
        #pragma unroll
        for (int r = 0; r < 4; ++r) {
            const int qrow = q0 + wave * 16 + fq * 4 + r;
            out[((size_t)(b * S + qrow)) * Dm + h * 64 + d * 16 + fr] = oacc[d][r] * inv[r];
        }
    }
}

// ---------------------------------------------------------------------------
extern "C" void kernel_launch(void* const* d_in, const int* in_sizes, int n_in,
                              void* d_out, int out_size, void* d_ws, size_t ws_size,
                              hipStream_t stream)
{
    const float* query = (const float*)d_in[0];
    const float* key_  = (const float*)d_in[1];
    const float* value = (const float*)d_in[2];
    const int*   amask = (const int*)d_in[3];
    const float* Wq = (const float*)d_in[4];
    const float* bq = (const float*)d_in[5];
    const float* Wk = (const float*)d_in[6];
    const float* bk = (const float*)d_in[7];
    const float* Wv = (const float*)d_in[8];
    const float* bv = (const float*)d_in[9];
    float* out = (float*)d_out;

    const size_t MD = (size_t)4096 * 1024;
    unsigned short* Qw = (unsigned short*)d_ws;
    unsigned short* Kw = Qw + MD;
    unsigned short* Vw = Kw + MD;

    dim3 gg(256, 3);
    hipLaunchKernelGGL(proj_gemm, gg, dim3(256), 0, stream,
                       query, key_, value, Wq, Wk, Wv, bq, bk, bv, Qw, Kw, Vw);
    dim3 ag(16, 16, 4);
    hipLaunchKernelGGL(attn_fwd, ag, dim3(256), 0, stream, Qw, Kw, Vw, amask, out);
}

// Round 2
// 167.226 us; speedup vs baseline: 1.3531x; 1.3531x over previous
//
#include <hip/hip_runtime.h>
#include <hip/hip_bf16.h>

using f32x4  = __attribute__((ext_vector_type(4))) float;
using bf16x8 = __attribute__((ext_vector_type(8))) __bf16;
using u16x8  = __attribute__((ext_vector_type(8))) unsigned short;

static __device__ __forceinline__ unsigned short f2bf(float f) {
    unsigned u = __builtin_bit_cast(unsigned, f);
    u += 0x7FFF + ((u >> 16) & 1);   // round-to-nearest-even
    return (unsigned short)(u >> 16);
}

static __device__ __forceinline__ void gload_lds16(const unsigned short* g, unsigned short* l) {
    __builtin_amdgcn_global_load_lds(
        (const __attribute__((address_space(1))) unsigned int*)g,
        (__attribute__((address_space(3))) unsigned int*)l, 16, 0, 0);
}

// ---------------------------------------------------------------------------
// Kernel 0: fp32 -> bf16 convert. blockIdx.y selects tensor (0-2: X, 3-5: W).
// ---------------------------------------------------------------------------
__global__ __launch_bounds__(256) void cvt6(
    const float* __restrict__ s0, const float* __restrict__ s1, const float* __restrict__ s2,
    const float* __restrict__ s3, const float* __restrict__ s4, const float* __restrict__ s5,
    unsigned short* __restrict__ d0, unsigned short* __restrict__ d1, unsigned short* __restrict__ d2,
    unsigned short* __restrict__ d3, unsigned short* __restrict__ d4, unsigned short* __restrict__ d5)
{
    const int y = blockIdx.y;
    const float* s = y == 0 ? s0 : y == 1 ? s1 : y == 2 ? s2 : y == 3 ? s3 : y == 4 ? s4 : s5;
    unsigned short* d = y == 0 ? d0 : y == 1 ? d1 : y == 2 ? d2 : y == 3 ? d3 : y == 4 ? d4 : d5;
    const int n = (y < 3) ? 4 * 1024 * 1024 : 1024 * 1024;
    const int stride = gridDim.x * 256 * 8;
    for (int i = (blockIdx.x * 256 + threadIdx.x) * 8; i < n; i += stride) {
        f32x4 a = *(const f32x4*)(s + i);
        f32x4 b = *(const f32x4*)(s + i + 4);
        u16x8 o;
        o[0] = f2bf(a.x); o[1] = f2bf(a.y); o[2] = f2bf(a.z); o[3] = f2bf(a.w);
        o[4] = f2bf(b.x); o[5] = f2bf(b.y); o[6] = f2bf(b.z); o[7] = f2bf(b.w);
        *(u16x8*)(d + i) = o;
    }
}

// ---------------------------------------------------------------------------
// Kernel 1 (m97 structure): Y = X @ W^T + bias, all bf16 operands.
// 128x128 tile, BK=32, linear LDS [128][32], global_load_lds width 16,
// 2-barrier K-loop, 4 waves x 4x4 mfma_f32_16x16x32_bf16.
// ---------------------------------------------------------------------------
__global__ __launch_bounds__(256) void gemm_bt(
    const unsigned short* __restrict__ A0, const unsigned short* __restrict__ A1, const unsigned short* __restrict__ A2,
    const unsigned short* __restrict__ B0, const unsigned short* __restrict__ B1, const unsigned short* __restrict__ B2,
    const float* __restrict__ b0, const float* __restrict__ b1, const float* __restrict__ b2,
    unsigned short* __restrict__ O0, unsigned short* __restrict__ O1, unsigned short* __restrict__ O2)
{
    const int N = 1024, K = 1024;
    const int which = blockIdx.y;
    const unsigned short* A = which == 0 ? A0 : (which == 1 ? A1 : A2);
    const unsigned short* B = which == 0 ? B0 : (which == 1 ? B1 : B2);
    const float* bias = which == 0 ? b0 : (which == 1 ? b1 : b2);
    unsigned short* O = which == 0 ? O0 : (which == 1 ? O1 : O2);

    const int bm = blockIdx.x >> 3;   // 32 row tiles
    const int bn = blockIdx.x & 7;    // 8 col tiles
    const int row0 = bm * 128, col0 = bn * 128;

    __shared__ __align__(16) unsigned short As[128 * 32];
    __shared__ __align__(16) unsigned short Bs[128 * 32];

    const int t = threadIdx.x;
    const int lane = t & 63;
    const int wave = t >> 6;
    const int wr = (wave >> 1) * 64, wc = (wave & 1) * 64;
    const int fr = lane & 15;
    const int fq = lane >> 4;

    f32x4 acc[4][4] = {};

    // staging geometry: seg = c*256 + t covers [128 rows][4 x 16B]
    const int r0s = t >> 2, k0s = (t & 3) * 8;          // seg c=0
    const int r1s = (t + 256) >> 2, k1s = (t & 3) * 8;  // seg c=1
    unsigned short* ldsA0 = &As[(wave * 64) * 8];
    unsigned short* ldsA1 = &As[(256 + wave * 64) * 8];
    unsigned short* ldsB0 = &Bs[(wave * 64) * 8];
    unsigned short* ldsB1 = &Bs[(256 + wave * 64) * 8];

    for (int k0 = 0; k0 < K; k0 += 32) {
        gload_lds16(A + (size_t)(row0 + r0s) * K + k0 + k0s, ldsA0);
        gload_lds16(A + (size_t)(row0 + r1s) * K + k0 + k1s, ldsA1);
        gload_lds16(B + (size_t)(col0 + r0s) * K + k0 + k0s, ldsB0);
        gload_lds16(B + (size_t)(col0 + r1s) * K + k0 + k1s, ldsB1);
        __syncthreads();

        bf16x8 af[4], bfr[4];
        #pragma unroll
        for (int m = 0; m < 4; ++m)
            af[m] = *(const bf16x8*)(&As[(wr + m * 16 + fr) * 32 + fq * 8]);
        #pragma unroll
        for (int n = 0; n < 4; ++n)
            bfr[n] = *(const bf16x8*)(&Bs[(wc + n * 16 + fr) * 32 + fq * 8]);
        #pragma unroll
        for (int m = 0; m < 4; ++m)
            #pragma unroll
            for (int n = 0; n < 4; ++n)
                acc[m][n] = __builtin_amdgcn_mfma_f32_16x16x32_bf16(af[m], bfr[n], acc[m][n], 0, 0, 0);
        __syncthreads();
    }

    #pragma unroll
    for (int n = 0; n < 4; ++n) {
        const int col = col0 + wc + n * 16 + fr;
        const float bv = bias[col];
        #pragma unroll
        for (int m = 0; m < 4; ++m) {
            #pragma unroll
            for (int r = 0; r < 4; ++r) {
                const int row = row0 + wr + m * 16 + fq * 4 + r;
                O[(size_t)row * N + col] = f2bf(acc[m][n][r] + bv);
            }
        }
    }
}

// ---------------------------------------------------------------------------
// Kernel 2: causal flash attention per (b, h, 64-row q-block). 4 waves,
// wave owns 16 q-rows. K-tiles of 32. Online softmax in-register.
// ---------------------------------------------------------------------------
#define QB 64
#define KB 32
#define KLD 72
#define VLD 40
#define PLD 40

__global__ __launch_bounds__(256, 2) void attn_fwd(
    const unsigned short* __restrict__ Qw, const unsigned short* __restrict__ Kw,
    const unsigned short* __restrict__ Vw, const int* __restrict__ amask,
    float* __restrict__ out)
{
    const int S = 1024, Dm = 1024;
    const int qb = blockIdx.x, h = blockIdx.y, b = blockIdx.z;
    const int q0 = qb * QB;
    const int t = threadIdx.x, lane = t & 63, wave = t >> 6;
    const int fr = lane & 15, fq = lane >> 4;

    __shared__ __align__(16) unsigned short Ks[KB][KLD];
    __shared__ __align__(16) unsigned short Vts[64][VLD];
    __shared__ __align__(16) unsigned short Ps[4][16][PLD];

    const int qrowA = q0 + wave * 16 + fr;
    const size_t qbase = ((size_t)(b * S + qrowA)) * Dm + h * 64;
    bf16x8 qf[2];
    qf[0] = *(const bf16x8*)(Qw + qbase + fq * 8);
    qf[1] = *(const bf16x8*)(Qw + qbase + 32 + fq * 8);

    f32x4 oacc[4] = {};
    float mrow[4], lrow[4];
    #pragma unroll
    for (int r = 0; r < 4; ++r) { mrow[r] = -3.0e38f; lrow[r] = 0.f; }

    const int nkt = (q0 + QB) / KB;
    const int srow = t >> 3;
    const int scol = (t & 7) * 8;

    for (int kt = 0; kt < nkt; ++kt) {
        const int k0 = kt * KB;
        __syncthreads();
        {
            const size_t g = ((size_t)(b * S + k0 + srow)) * Dm + h * 64 + scol;
            *(bf16x8*)(&Ks[srow][scol]) = *(const bf16x8*)(Kw + g);
            bf16x8 v = *(const bf16x8*)(Vw + g);
            #pragma unroll
            for (int j = 0; j < 8; ++j)
                Vts[scol + j][srow] = ((const unsigned short*)&v)[j];
        }
        __syncthreads();

        f32x4 sfr[2];
        #pragma unroll
        for (int nf = 0; nf < 2; ++nf) {
            bf16x8 kb0 = *(const bf16x8*)(&Ks[nf * 16 + fr][fq * 8]);
            bf16x8 kb1 = *(const bf16x8*)(&Ks[nf * 16 + fr][32 + fq * 8]);
            f32x4 z = {};
            z = __builtin_amdgcn_mfma_f32_16x16x32_bf16(qf[0], kb0, z, 0, 0, 0);
            z = __builtin_amdgcn_mfma_f32_16x16x32_bf16(qf[1], kb1, z, 0, 0, 0);
            sfr[nf] = z;
        }

        float sv[2][4];
        #pragma unroll
        for (int nf = 0; nf < 2; ++nf) {
            const int kpos = k0 + nf * 16 + fr;
            const int mk = amask[b * S + kpos];
            #pragma unroll
            for (int r = 0; r < 4; ++r) {
                const int qrow = q0 + wave * 16 + fq * 4 + r;
                float v = sfr[nf][r] * 0.125f;
                if (kpos > qrow || mk == 0) v = -3.0e38f;
                sv[nf][r] = v;
            }
        }

        #pragma unroll
        for (int r = 0; r < 4; ++r) {
            float v = fmaxf(sv[0][r], sv[1][r]);
            v = fmaxf(v, __shfl_xor(v, 1));
            v = fmaxf(v, __shfl_xor(v, 2));
            v = fmaxf(v, __shfl_xor(v, 4));
            v = fmaxf(v, __shfl_xor(v, 8));
            const float mn = fmaxf(mrow[r], v);
            const float sc = __expf(mrow[r] - mn);
            mrow[r] = mn;
            lrow[r] *= sc;
            #pragma unroll
            for (int d = 0; d < 4; ++d) oacc[d][r] *= sc;
        }

        float rs[4] = {0.f, 0.f, 0.f, 0.f};
        #pragma unroll
        for (int nf = 0; nf < 2; ++nf) {
            #pragma unroll
            for (int r = 0; r < 4; ++r) {
                const float p = (sv[nf][r] < -1.0e37f) ? 0.f : __expf(sv[nf][r] - mrow[r]);
                rs[r] += p;
                Ps[wave][fq * 4 + r][nf * 16 + fr] = f2bf(p);
            }
        }
        #pragma unroll
        for (int r = 0; r < 4; ++r) {
            float v = rs[r];
            v += __shfl_xor(v, 1);
            v += __shfl_xor(v, 2);
            v += __shfl_xor(v, 4);
            v += __shfl_xor(v, 8);
            lrow[r] += v;
        }

        bf16x8 pa = *(const bf16x8*)(&Ps[wave][fr][fq * 8]);
        #pragma unroll
        for (int d = 0; d < 4; ++d) {
            bf16x8 vb = *(const bf16x8*)(&Vts[d * 16 + fr][fq * 8]);
            oacc[d] = __builtin_amdgcn_mfma_f32_16x16x32_bf16(pa, vb, oacc[d], 0, 0, 0);
        }
    }

    float inv[4];
    #pragma unroll
    for (int r = 0; r < 4; ++r) inv[r] = 1.0f / lrow[r];
    #pragma unroll
    for (int d = 0; d < 4; ++d) {
        #pragma unroll
        for (int r = 0; r < 4; ++r) {
            const int qrow = q0 + wave * 16 + fq * 4 + r;
            out[((size_t)(b * S + qrow)) * Dm + h * 64 + d * 16 + fr] = oacc[d][r] * inv[r];
        }
    }
}

// ---------------------------------------------------------------------------
extern "C" void kernel_launch(void* const* d_in, const int* in_sizes, int n_in,
                              void* d_out, int out_size, void* d_ws, size_t ws_size,
                              hipStream_t stream)
{
    const float* query = (const float*)d_in[0];
    const float* key_  = (const float*)d_in[1];
    const float* value = (const float*)d_in[2];
    const int*   amask = (const int*)d_in[3];
    const float* Wq = (const float*)d_in[4];
    const float* bq = (const float*)d_in[5];
    const float* Wk = (const float*)d_in[6];
    const float* bk = (const float*)d_in[7];
    const float* Wv = (const float*)d_in[8];
    const float* bv = (const float*)d_in[9];
    float* out = (float*)d_out;

    const size_t MD = (size_t)4096 * 1024;   // 4 Mi elems
    const size_t WD = (size_t)1024 * 1024;   // 1 Mi elems
    unsigned short* Qw  = (unsigned short*)d_ws;
    unsigned short* Kw  = Qw + MD;
    unsigned short* Vw  = Kw + MD;
    unsigned short* Xq  = Vw + MD;
    unsigned short* Xk  = Xq + MD;
    unsigned short* Xv  = Xk + MD;
    unsigned short* Wqb = Xv + MD;
    unsigned short* Wkb = Wqb + WD;
    unsigned short* Wvb = Wkb + WD;

    // 1) fp32 -> bf16
    hipLaunchKernelGGL(cvt6, dim3(512, 6), dim3(256), 0, stream,
                       query, key_, value, Wq, Wk, Wv,
                       Xq, Xk, Xv, Wqb, Wkb, Wvb);
    // 2) projections
    hipLaunchKernelGGL(gemm_bt, dim3(256, 3), dim3(256), 0, stream,
                       Xq, Xk, Xv, Wqb, Wkb, Wvb, bq, bk, bv, Qw, Kw, Vw);
    // 3) attention
    hipLaunchKernelGGL(attn_fwd, dim3(16, 16, 4), dim3(256), 0, stream,
                       Qw, Kw, Vw, amask, out);
}

// Round 3
// 122.842 us; speedup vs baseline: 1.8421x; 1.3613x over previous
//
#include <hip/hip_runtime.h>
#include <hip/hip_bf16.h>

using f32x4  = __attribute__((ext_vector_type(4))) float;
using bf16x8 = __attribute__((ext_vector_type(8))) __bf16;
using u16x8  = __attribute__((ext_vector_type(8))) unsigned short;

#define QSCALE 0.18033688f   // 0.125 * log2(e): scores pre-scaled into exp2 domain

static __device__ __forceinline__ unsigned short f2bf(float f) {
    unsigned u = __builtin_bit_cast(unsigned, f);
    u += 0x7FFF + ((u >> 16) & 1);   // RNE
    return (unsigned short)(u >> 16);
}

static __device__ __forceinline__ void gload_lds16(const unsigned short* g, unsigned short* l) {
    __builtin_amdgcn_global_load_lds(
        (const __attribute__((address_space(1))) unsigned int*)g,
        (__attribute__((address_space(3))) unsigned int*)l, 16, 0, 0);
}

// ---------------------------------------------------------------------------
// Kernel 0: fp32 -> bf16 convert (X q/k/v, W q/k/v).
// ---------------------------------------------------------------------------
__global__ __launch_bounds__(256) void cvt6(
    const float* __restrict__ s0, const float* __restrict__ s1, const float* __restrict__ s2,
    const float* __restrict__ s3, const float* __restrict__ s4, const float* __restrict__ s5,
    unsigned short* __restrict__ d0, unsigned short* __restrict__ d1, unsigned short* __restrict__ d2,
    unsigned short* __restrict__ d3, unsigned short* __restrict__ d4, unsigned short* __restrict__ d5)
{
    const int y = blockIdx.y;
    const float* s = y == 0 ? s0 : y == 1 ? s1 : y == 2 ? s2 : y == 3 ? s3 : y == 4 ? s4 : s5;
    unsigned short* d = y == 0 ? d0 : y == 1 ? d1 : y == 2 ? d2 : y == 3 ? d3 : y == 4 ? d4 : d5;
    const int n = (y < 3) ? 4 * 1024 * 1024 : 1024 * 1024;
    const int stride = gridDim.x * 256 * 8;
    for (int i = (blockIdx.x * 256 + threadIdx.x) * 8; i < n; i += stride) {
        f32x4 a = *(const f32x4*)(s + i);
        f32x4 b = *(const f32x4*)(s + i + 4);
        u16x8 o;
        o[0] = f2bf(a.x); o[1] = f2bf(a.y); o[2] = f2bf(a.z); o[3] = f2bf(a.w);
        o[4] = f2bf(b.x); o[5] = f2bf(b.y); o[6] = f2bf(b.z); o[7] = f2bf(b.w);
        *(u16x8*)(d + i) = o;
    }
}

// ---------------------------------------------------------------------------
// Kernel 1 (m97 structure): Y = X @ W^T + bias, bf16 operands.
// which==0 (Q): output scaled by QSCALE.  which==2 (V): output written
// TRANSPOSED per head: Vt[(b*16+h)*64+dk][1024 s] (8B contiguous stores).
// ---------------------------------------------------------------------------
__global__ __launch_bounds__(256) void gemm_bt(
    const unsigned short* __restrict__ A0, const unsigned short* __restrict__ A1, const unsigned short* __restrict__ A2,
    const unsigned short* __restrict__ B0, const unsigned short* __restrict__ B1, const unsigned short* __restrict__ B2,
    const float* __restrict__ b0, const float* __restrict__ b1, const float* __restrict__ b2,
    unsigned short* __restrict__ O0, unsigned short* __restrict__ O1, unsigned short* __restrict__ O2)
{
    const int N = 1024, K = 1024;
    const int which = blockIdx.y;
    const unsigned short* A = which == 0 ? A0 : (which == 1 ? A1 : A2);
    const unsigned short* B = which == 0 ? B0 : (which == 1 ? B1 : B2);
    const float* bias = which == 0 ? b0 : (which == 1 ? b1 : b2);
    unsigned short* O = which == 0 ? O0 : (which == 1 ? O1 : O2);

    const int bm = blockIdx.x >> 3;
    const int bn = blockIdx.x & 7;
    const int row0 = bm * 128, col0 = bn * 128;

    __shared__ __align__(16) unsigned short As[128 * 32];
    __shared__ __align__(16) unsigned short Bs[128 * 32];

    const int t = threadIdx.x;
    const int lane = t & 63;
    const int wave = t >> 6;
    const int wr = (wave >> 1) * 64, wc = (wave & 1) * 64;
    const int fr = lane & 15;
    const int fq = lane >> 4;

    f32x4 acc[4][4] = {};

    const int r0s = t >> 2, k0s = (t & 3) * 8;
    const int r1s = (t + 256) >> 2, k1s = (t & 3) * 8;
    unsigned short* ldsA0 = &As[(wave * 64) * 8];
    unsigned short* ldsA1 = &As[(256 + wave * 64) * 8];
    unsigned short* ldsB0 = &Bs[(wave * 64) * 8];
    unsigned short* ldsB1 = &Bs[(256 + wave * 64) * 8];

    for (int k0 = 0; k0 < K; k0 += 32) {
        gload_lds16(A + (size_t)(row0 + r0s) * K + k0 + k0s, ldsA0);
        gload_lds16(A + (size_t)(row0 + r1s) * K + k0 + k1s, ldsA1);
        gload_lds16(B + (size_t)(col0 + r0s) * K + k0 + k0s, ldsB0);
        gload_lds16(B + (size_t)(col0 + r1s) * K + k0 + k1s, ldsB1);
        __syncthreads();

        bf16x8 af[4], bfr[4];
        #pragma unroll
        for (int m = 0; m < 4; ++m)
            af[m] = *(const bf16x8*)(&As[(wr + m * 16 + fr) * 32 + fq * 8]);
        #pragma unroll
        for (int n = 0; n < 4; ++n)
            bfr[n] = *(const bf16x8*)(&Bs[(wc + n * 16 + fr) * 32 + fq * 8]);
        #pragma unroll
        for (int m = 0; m < 4; ++m)
            #pragma unroll
            for (int n = 0; n < 4; ++n)
                acc[m][n] = __builtin_amdgcn_mfma_f32_16x16x32_bf16(af[m], bfr[n], acc[m][n], 0, 0, 0);
        __syncthreads();
    }

    if (which == 2) {
        // V: write transposed per-head: Vt[(b*16+h)*64+dk][s]
        #pragma unroll
        for (int n = 0; n < 4; ++n) {
            const int col = col0 + wc + n * 16 + fr;        // d-dim
            const int h = col >> 6, dk = col & 63;
            const float bv = bias[col];
            #pragma unroll
            for (int m = 0; m < 4; ++m) {
                const int rowb = row0 + wr + m * 16 + fq * 4;  // b*1024 + s
                const int bb = rowb >> 10, s = rowb & 1023;
                ushort4 o;
                o.x = f2bf(acc[m][n][0] + bv);
                o.y = f2bf(acc[m][n][1] + bv);
                o.z = f2bf(acc[m][n][2] + bv);
                o.w = f2bf(acc[m][n][3] + bv);
                *(ushort4*)(O + ((size_t)((bb * 16 + h) * 64 + dk)) * 1024 + s) = o;
            }
        }
    } else {
        const float sc = (which == 0) ? QSCALE : 1.0f;
        #pragma unroll
        for (int n = 0; n < 4; ++n) {
            const int col = col0 + wc + n * 16 + fr;
            const float bv = bias[col];
            #pragma unroll
            for (int m = 0; m < 4; ++m) {
                #pragma unroll
                for (int r = 0; r < 4; ++r) {
                    const int row = row0 + wr + m * 16 + fq * 4 + r;
                    O[(size_t)row * N + col] = f2bf((acc[m][n][r] + bv) * sc);
                }
            }
        }
    }
}

// ---------------------------------------------------------------------------
// Kernel 2: causal flash attention. Block = 4 waves, 64 q-rows; processes two
// q-blocks (pi and 15-pi) for uniform 17-tile load. K-tile = 64, K staged in
// padded LDS; V-fragments read directly from global Vt (L2-resident).
// Scores arrive pre-scaled into exp2 domain (QSCALE folded into Q).
// ---------------------------------------------------------------------------
__global__ __launch_bounds__(256) void attn_fwd(
    const unsigned short* __restrict__ Qw, const unsigned short* __restrict__ Kw,
    const unsigned short* __restrict__ Vt, const int* __restrict__ amask,
    float* __restrict__ out)
{
    const int S = 1024, Dm = 1024;
    const int pi = blockIdx.x;          // 0..7
    const int h = blockIdx.y, b = blockIdx.z;
    const int t = threadIdx.x, lane = t & 63, wave = t >> 6;
    const int fr = lane & 15, fq = lane >> 4;

    __shared__ __align__(16) unsigned short Ks[64][72];
    __shared__ __align__(16) unsigned short Ps[4][16][72];

    const size_t kbase = (size_t)b * S * Dm + h * 64;
    const size_t vtbase = (size_t)((b * 16 + h) * 64) * S;

    for (int qi = 0; qi < 2; ++qi) {
        const int qb = (qi == 0) ? pi : 15 - pi;
        const int q0 = qb * 64;

        const int qrowA = q0 + wave * 16 + fr;
        const size_t qbp = (size_t)(b * S + qrowA) * Dm + h * 64;
        const bf16x8 qf0 = *(const bf16x8*)(Qw + qbp + fq * 8);
        const bf16x8 qf1 = *(const bf16x8*)(Qw + qbp + 32 + fq * 8);

        f32x4 oacc[4] = {};
        float mrow[4], lpart[4];
        #pragma unroll
        for (int r = 0; r < 4; ++r) { mrow[r] = -3.0e38f; lpart[r] = 0.f; }

        const int nkt = qb + 1;
        for (int kt = 0; kt < nkt; ++kt) {
            const int k0 = kt * 64;
            __syncthreads();
            #pragma unroll
            for (int i = 0; i < 2; ++i) {      // stage K tile [64][64] -> [64][72]
                const int idx = t + i * 256;
                const int r_ = idx >> 3, c_ = (idx & 7) * 8;
                *(bf16x8*)(&Ks[r_][c_]) = *(const bf16x8*)(Kw + kbase + (size_t)(k0 + r_) * Dm + c_);
            }
            __syncthreads();

            // V-fragments direct from global (issue early; consumed by PV)
            bf16x8 vb[4][2];
            #pragma unroll
            for (int d = 0; d < 4; ++d)
                #pragma unroll
                for (int kc = 0; kc < 2; ++kc)
                    vb[d][kc] = *(const bf16x8*)(Vt + vtbase + (size_t)(d * 16 + fr) * S + k0 + kc * 32 + fq * 8);

            // S = Q K^T (pre-scaled)
            f32x4 sfr[4];
            #pragma unroll
            for (int nf = 0; nf < 4; ++nf) {
                const bf16x8 kb0 = *(const bf16x8*)(&Ks[nf * 16 + fr][fq * 8]);
                const bf16x8 kb1 = *(const bf16x8*)(&Ks[nf * 16 + fr][32 + fq * 8]);
                f32x4 z = {};
                z = __builtin_amdgcn_mfma_f32_16x16x32_bf16(qf0, kb0, z, 0, 0, 0);
                z = __builtin_amdgcn_mfma_f32_16x16x32_bf16(qf1, kb1, z, 0, 0, 0);
                sfr[nf] = z;
            }

            // att_mask (fast path: all ones)
            const int mk = amask[b * S + k0 + lane];
            if (!__all(mk != 0)) {
                #pragma unroll
                for (int nf = 0; nf < 4; ++nf) {
                    const float pen = (amask[b * S + k0 + nf * 16 + fr] == 0) ? -3.0e38f : 0.f;
                    #pragma unroll
                    for (int r = 0; r < 4; ++r) sfr[nf][r] += pen;
                }
            }
            // causal: only the diagonal tile
            if (kt == nkt - 1) {
                #pragma unroll
                for (int nf = 0; nf < 4; ++nf) {
                    const int kpos = k0 + nf * 16 + fr;
                    #pragma unroll
                    for (int r = 0; r < 4; ++r) {
                        const int qr = q0 + wave * 16 + fq * 4 + r;
                        if (kpos > qr) sfr[nf][r] = -3.0e38f;
                    }
                }
            }

            // defer-max: per-lane max; rescale only if some row grew > THR
            float plm[4];
            #pragma unroll
            for (int r = 0; r < 4; ++r)
                plm[r] = fmaxf(fmaxf(sfr[0][r], sfr[1][r]), fmaxf(sfr[2][r], sfr[3][r]));
            float grow = plm[0] - mrow[0];
            #pragma unroll
            for (int r = 1; r < 4; ++r) grow = fmaxf(grow, plm[r] - mrow[r]);
            if (!__all(grow <= 8.0f)) {
                #pragma unroll
                for (int r = 0; r < 4; ++r) {
                    float v = plm[r];
                    v = fmaxf(v, __shfl_xor(v, 1));
                    v = fmaxf(v, __shfl_xor(v, 2));
                    v = fmaxf(v, __shfl_xor(v, 4));
                    v = fmaxf(v, __shfl_xor(v, 8));
                    const float mn = fmaxf(mrow[r], v);
                    const float sc = exp2f(mrow[r] - mn);
                    mrow[r] = mn;
                    lpart[r] *= sc;
                    #pragma unroll
                    for (int d = 0; d < 4; ++d) oacc[d][r] *= sc;
                }
            }

            // p = exp2(s - m) (masked -3e38 -> 0 naturally); per-lane partial sums
            #pragma unroll
            for (int nf = 0; nf < 4; ++nf) {
                #pragma unroll
                for (int r = 0; r < 4; ++r) {
                    const float p = exp2f(sfr[nf][r] - mrow[r]);
                    lpart[r] += p;
                    Ps[wave][fq * 4 + r][nf * 16 + fr] = f2bf(p);
                }
            }

            // O += P V
            const bf16x8 pa0 = *(const bf16x8*)(&Ps[wave][fr][fq * 8]);
            const bf16x8 pa1 = *(const bf16x8*)(&Ps[wave][fr][32 + fq * 8]);
            #pragma unroll
            for (int d = 0; d < 4; ++d) {
                oacc[d] = __builtin_amdgcn_mfma_f32_16x16x32_bf16(pa0, vb[d][0], oacc[d], 0, 0, 0);
                oacc[d] = __builtin_amdgcn_mfma_f32_16x16x32_bf16(pa1, vb[d][1], oacc[d], 0, 0, 0);
            }
        }

        // epilogue: reduce per-lane partial sums across fr, normalize, store
        float inv[4];
        #pragma unroll
        for (int r = 0; r < 4; ++r) {
            float v = lpart[r];
            v += __shfl_xor(v, 1);
            v += __shfl_xor(v, 2);
            v += __shfl_xor(v, 4);
            v += __shfl_xor(v, 8);
            inv[r] = 1.0f / v;
        }
        #pragma unroll
        for (int d = 0; d < 4; ++d)
            #pragma unroll
            for (int r = 0; r < 4; ++r) {
                const int qr = q0 + wave * 16 + fq * 4 + r;
                out[(size_t)(b * S + qr) * Dm + h * 64 + d * 16 + fr] = oacc[d][r] * inv[r];
            }
    }
}

// ---------------------------------------------------------------------------
extern "C" void kernel_launch(void* const* d_in, const int* in_sizes, int n_in,
                              void* d_out, int out_size, void* d_ws, size_t ws_size,
                              hipStream_t stream)
{
    const float* query = (const float*)d_in[0];
    const float* key_  = (const float*)d_in[1];
    const float* value = (const float*)d_in[2];
    const int*   amask = (const int*)d_in[3];
    const float* Wq = (const float*)d_in[4];
    const float* bq = (const float*)d_in[5];
    const float* Wk = (const float*)d_in[6];
    const float* bk = (const float*)d_in[7];
    const float* Wv = (const float*)d_in[8];
    const float* bv = (const float*)d_in[9];
    float* out = (float*)d_out;

    const size_t MD = (size_t)4096 * 1024;
    const size_t WD = (size_t)1024 * 1024;
    unsigned short* Qw  = (unsigned short*)d_ws;
    unsigned short* Kw  = Qw + MD;
    unsigned short* Vtw = Kw + MD;
    unsigned short* Xq  = Vtw + MD;
    unsigned short* Xk  = Xq + MD;
    unsigned short* Xv  = Xk + MD;
    unsigned short* Wqb = Xv + MD;
    unsigned short* Wkb = Wqb + WD;
    unsigned short* Wvb = Wkb + WD;

    hipLaunchKernelGGL(cvt6, dim3(512, 6), dim3(256), 0, stream,
                       query, key_, value, Wq, Wk, Wv,
                       Xq, Xk, Xv, Wqb, Wkb, Wvb);
    hipLaunchKernelGGL(gemm_bt, dim3(256, 3), dim3(256), 0, stream,
                       Xq, Xk, Xv, Wqb, Wkb, Wvb, bq, bk, bv, Qw, Kw, Vtw);
    hipLaunchKernelGGL(attn_fwd, dim3(8, 16, 4), dim3(256), 0, stream,
                       Qw, Kw, Vtw, amask, out);
}

// Round 4
// 115.674 us; speedup vs baseline: 1.9562x; 1.0620x over previous
//
#include <hip/hip_runtime.h>
#include <hip/hip_bf16.h>

using f32x4  = __attribute__((ext_vector_type(4))) float;
using bf16x8 = __attribute__((ext_vector_type(8))) __bf16;
using u16x8  = __attribute__((ext_vector_type(8))) unsigned short;

#define QSCALE 0.18033688f   // 0.125 * log2(e): scores pre-scaled into exp2 domain

static __device__ __forceinline__ unsigned short f2bf(float f) {
    unsigned u = __builtin_bit_cast(unsigned, f);
    u += 0x7FFF + ((u >> 16) & 1);   // RNE
    return (unsigned short)(u >> 16);
}

static __device__ __forceinline__ void gload_lds16(const unsigned short* g, unsigned short* l) {
    __builtin_amdgcn_global_load_lds(
        (const __attribute__((address_space(1))) unsigned int*)g,
        (__attribute__((address_space(3))) unsigned int*)l, 16, 0, 0);
}

// ---------------------------------------------------------------------------
// Kernel 0: fp32 -> bf16 convert (X q/k/v, W q/k/v).
// ---------------------------------------------------------------------------
__global__ __launch_bounds__(256) void cvt6(
    const float* __restrict__ s0, const float* __restrict__ s1, const float* __restrict__ s2,
    const float* __restrict__ s3, const float* __restrict__ s4, const float* __restrict__ s5,
    unsigned short* __restrict__ d0, unsigned short* __restrict__ d1, unsigned short* __restrict__ d2,
    unsigned short* __restrict__ d3, unsigned short* __restrict__ d4, unsigned short* __restrict__ d5)
{
    const int y = blockIdx.y;
    const float* s = y == 0 ? s0 : y == 1 ? s1 : y == 2 ? s2 : y == 3 ? s3 : y == 4 ? s4 : s5;
    unsigned short* d = y == 0 ? d0 : y == 1 ? d1 : y == 2 ? d2 : y == 3 ? d3 : y == 4 ? d4 : d5;
    const int n = (y < 3) ? 4 * 1024 * 1024 : 1024 * 1024;
    const int stride = gridDim.x * 256 * 8;
    for (int i = (blockIdx.x * 256 + threadIdx.x) * 8; i < n; i += stride) {
        f32x4 a = *(const f32x4*)(s + i);
        f32x4 b = *(const f32x4*)(s + i + 4);
        u16x8 o;
        o[0] = f2bf(a.x); o[1] = f2bf(a.y); o[2] = f2bf(a.z); o[3] = f2bf(a.w);
        o[4] = f2bf(b.x); o[5] = f2bf(b.y); o[6] = f2bf(b.z); o[7] = f2bf(b.w);
        *(u16x8*)(d + i) = o;
    }
}

// ---------------------------------------------------------------------------
// Kernel 1 (m97 structure, round-2 form): Y = X @ W^T + bias, bf16 operands.
// Uniform thin epilogue; which==0 (Q) additionally scaled by QSCALE.
// ---------------------------------------------------------------------------
__global__ __launch_bounds__(256) void gemm_bt(
    const unsigned short* __restrict__ A0, const unsigned short* __restrict__ A1, const unsigned short* __restrict__ A2,
    const unsigned short* __restrict__ B0, const unsigned short* __restrict__ B1, const unsigned short* __restrict__ B2,
    const float* __restrict__ b0, const float* __restrict__ b1, const float* __restrict__ b2,
    unsigned short* __restrict__ O0, unsigned short* __restrict__ O1, unsigned short* __restrict__ O2)
{
    const int N = 1024, K = 1024;
    const int which = blockIdx.y;
    const unsigned short* A = which == 0 ? A0 : (which == 1 ? A1 : A2);
    const unsigned short* B = which == 0 ? B0 : (which == 1 ? B1 : B2);
    const float* bias = which == 0 ? b0 : (which == 1 ? b1 : b2);
    unsigned short* O = which == 0 ? O0 : (which == 1 ? O1 : O2);

    const int bm = blockIdx.x >> 3;
    const int bn = blockIdx.x & 7;
    const int row0 = bm * 128, col0 = bn * 128;

    __shared__ __align__(16) unsigned short As[128 * 32];
    __shared__ __align__(16) unsigned short Bs[128 * 32];

    const int t = threadIdx.x;
    const int lane = t & 63;
    const int wave = t >> 6;
    const int wr = (wave >> 1) * 64, wc = (wave & 1) * 64;
    const int fr = lane & 15;
    const int fq = lane >> 4;

    f32x4 acc[4][4] = {};

    const int r0s = t >> 2, k0s = (t & 3) * 8;
    const int r1s = (t + 256) >> 2, k1s = (t & 3) * 8;
    unsigned short* ldsA0 = &As[(wave * 64) * 8];
    unsigned short* ldsA1 = &As[(256 + wave * 64) * 8];
    unsigned short* ldsB0 = &Bs[(wave * 64) * 8];
    unsigned short* ldsB1 = &Bs[(256 + wave * 64) * 8];

    for (int k0 = 0; k0 < K; k0 += 32) {
        gload_lds16(A + (size_t)(row0 + r0s) * K + k0 + k0s, ldsA0);
        gload_lds16(A + (size_t)(row0 + r1s) * K + k0 + k1s, ldsA1);
        gload_lds16(B + (size_t)(col0 + r0s) * K + k0 + k0s, ldsB0);
        gload_lds16(B + (size_t)(col0 + r1s) * K + k0 + k1s, ldsB1);
        __syncthreads();

        bf16x8 af[4], bfr[4];
        #pragma unroll
        for (int m = 0; m < 4; ++m)
            af[m] = *(const bf16x8*)(&As[(wr + m * 16 + fr) * 32 + fq * 8]);
        #pragma unroll
        for (int n = 0; n < 4; ++n)
            bfr[n] = *(const bf16x8*)(&Bs[(wc + n * 16 + fr) * 32 + fq * 8]);
        #pragma unroll
        for (int m = 0; m < 4; ++m)
            #pragma unroll
            for (int n = 0; n < 4; ++n)
                acc[m][n] = __builtin_amdgcn_mfma_f32_16x16x32_bf16(af[m], bfr[n], acc[m][n], 0, 0, 0);
        __syncthreads();
    }

    const float sc = (which == 0) ? QSCALE : 1.0f;
    #pragma unroll
    for (int n = 0; n < 4; ++n) {
        const int col = col0 + wc + n * 16 + fr;
        const float bv = bias[col];
        #pragma unroll
        for (int m = 0; m < 4; ++m) {
            #pragma unroll
            for (int r = 0; r < 4; ++r) {
                const int row = row0 + wr + m * 16 + fq * 4 + r;
                O[(size_t)row * N + col] = f2bf((acc[m][n][r] + bv) * sc);
            }
        }
    }
}

// ---------------------------------------------------------------------------
// Kernel 1b: V[b*S+s][h*64+dk] -> Vt[(b*16+h)*64+dk][s]. LDS 64x72 tile.
// ---------------------------------------------------------------------------
__global__ __launch_bounds__(256) void vtrans(
    const unsigned short* __restrict__ V, unsigned short* __restrict__ Vt)
{
    const int S = 1024, Dm = 1024;
    const int sb = blockIdx.x;      // 16 blocks of 64 s
    const int h = blockIdx.y, b = blockIdx.z;
    __shared__ __align__(16) unsigned short Lt[64][72];   // [dk][s], padded
    const int t = threadIdx.x;

    const int sl = t >> 3, dk0 = (t & 7) * 8;
    #pragma unroll
    for (int i = 0; i < 2; ++i) {
        const int s = sl + i * 32;
        u16x8 v = *(const u16x8*)(V + (size_t)(b * S + sb * 64 + s) * Dm + h * 64 + dk0);
        #pragma unroll
        for (int j = 0; j < 8; ++j)
            Lt[dk0 + j][s] = v[j];
    }
    __syncthreads();

    const int dk = t >> 2, scc = (t & 3) * 16;
    const size_t orow = ((size_t)((b * 16 + h) * 64 + dk)) * S + sb * 64;
    *(u16x8*)(Vt + orow + scc)     = *(const u16x8*)(&Lt[dk][scc]);
    *(u16x8*)(Vt + orow + scc + 8) = *(const u16x8*)(&Lt[dk][scc + 8]);
}

// ---------------------------------------------------------------------------
// Kernel 2: causal flash attention (unchanged structure; + setprio around
// MFMA clusters). Block = 4 waves, 64 q-rows; two q-blocks (pi, 15-pi).
// K-tile = 64 staged in padded LDS; V read directly from global Vt.
// ---------------------------------------------------------------------------
__global__ __launch_bounds__(256) void attn_fwd(
    const unsigned short* __restrict__ Qw, const unsigned short* __restrict__ Kw,
    const unsigned short* __restrict__ Vt, const int* __restrict__ amask,
    float* __restrict__ out)
{
    const int S = 1024, Dm = 1024;
    const int pi = blockIdx.x;
    const int h = blockIdx.y, b = blockIdx.z;
    const int t = threadIdx.x, lane = t & 63, wave = t >> 6;
    const int fr = lane & 15, fq = lane >> 4;

    __shared__ __align__(16) unsigned short Ks[64][72];
    __shared__ __align__(16) unsigned short Ps[4][16][72];

    const size_t kbase = (size_t)b * S * Dm + h * 64;
    const size_t vtbase = (size_t)((b * 16 + h) * 64) * S;

    for (int qi = 0; qi < 2; ++qi) {
        const int qb = (qi == 0) ? pi : 15 - pi;
        const int q0 = qb * 64;

        const int qrowA = q0 + wave * 16 + fr;
        const size_t qbp = (size_t)(b * S + qrowA) * Dm + h * 64;
        const bf16x8 qf0 = *(const bf16x8*)(Qw + qbp + fq * 8);
        const bf16x8 qf1 = *(const bf16x8*)(Qw + qbp + 32 + fq * 8);

        f32x4 oacc[4] = {};
        float mrow[4], lpart[4];
        #pragma unroll
        for (int r = 0; r < 4; ++r) { mrow[r] = -3.0e38f; lpart[r] = 0.f; }

        const int nkt = qb + 1;
        for (int kt = 0; kt < nkt; ++kt) {
            const int k0 = kt * 64;
            __syncthreads();
            #pragma unroll
            for (int i = 0; i < 2; ++i) {
                const int idx = t + i * 256;
                const int r_ = idx >> 3, c_ = (idx & 7) * 8;
                *(bf16x8*)(&Ks[r_][c_]) = *(const bf16x8*)(Kw + kbase + (size_t)(k0 + r_) * Dm + c_);
            }
            __syncthreads();

            bf16x8 vb[4][2];
            #pragma unroll
            for (int d = 0; d < 4; ++d)
                #pragma unroll
                for (int kc = 0; kc < 2; ++kc)
                    vb[d][kc] = *(const bf16x8*)(Vt + vtbase + (size_t)(d * 16 + fr) * S + k0 + kc * 32 + fq * 8);

            f32x4 sfr[4];
            __builtin_amdgcn_s_setprio(1);
            #pragma unroll
            for (int nf = 0; nf < 4; ++nf) {
                const bf16x8 kb0 = *(const bf16x8*)(&Ks[nf * 16 + fr][fq * 8]);
                const bf16x8 kb1 = *(const bf16x8*)(&Ks[nf * 16 + fr][32 + fq * 8]);
                f32x4 z = {};
                z = __builtin_amdgcn_mfma_f32_16x16x32_bf16(qf0, kb0, z, 0, 0, 0);
                z = __builtin_amdgcn_mfma_f32_16x16x32_bf16(qf1, kb1, z, 0, 0, 0);
                sfr[nf] = z;
            }
            __builtin_amdgcn_s_setprio(0);

            const int mk = amask[b * S + k0 + lane];
            if (!__all(mk != 0)) {
                #pragma unroll
                for (int nf = 0; nf < 4; ++nf) {
                    const float pen = (amask[b * S + k0 + nf * 16 + fr] == 0) ? -3.0e38f : 0.f;
                    #pragma unroll
                    for (int r = 0; r < 4; ++r) sfr[nf][r] += pen;
                }
            }
            if (kt == nkt - 1) {
                #pragma unroll
                for (int nf = 0; nf < 4; ++nf) {
                    const int kpos = k0 + nf * 16 + fr;
                    #pragma unroll
                    for (int r = 0; r < 4; ++r) {
                        const int qr = q0 + wave * 16 + fq * 4 + r;
                        if (kpos > qr) sfr[nf][r] = -3.0e38f;
                    }
                }
            }

            float plm[4];
            #pragma unroll
            for (int r = 0; r < 4; ++r)
                plm[r] = fmaxf(fmaxf(sfr[0][r], sfr[1][r]), fmaxf(sfr[2][r], sfr[3][r]));
            float grow = plm[0] - mrow[0];
            #pragma unroll
            for (int r = 1; r < 4; ++r) grow = fmaxf(grow, plm[r] - mrow[r]);
            if (!__all(grow <= 8.0f)) {
                #pragma unroll
                for (int r = 0; r < 4; ++r) {
                    float v = plm[r];
                    v = fmaxf(v, __shfl_xor(v, 1));
                    v = fmaxf(v, __shfl_xor(v, 2));
                    v = fmaxf(v, __shfl_xor(v, 4));
                    v = fmaxf(v, __shfl_xor(v, 8));
                    const float mn = fmaxf(mrow[r], v);
                    const float sc = exp2f(mrow[r] - mn);
                    mrow[r] = mn;
                    lpart[r] *= sc;
                    #pragma unroll
                    for (int d = 0; d < 4; ++d) oacc[d][r] *= sc;
                }
            }

            #pragma unroll
            for (int nf = 0; nf < 4; ++nf) {
                #pragma unroll
                for (int r = 0; r < 4; ++r) {
                    const float p = exp2f(sfr[nf][r] - mrow[r]);
                    lpart[r] += p;
                    Ps[wave][fq * 4 + r][nf * 16 + fr] = f2bf(p);
                }
            }

            const bf16x8 pa0 = *(const bf16x8*)(&Ps[wave][fr][fq * 8]);
            const bf16x8 pa1 = *(const bf16x8*)(&Ps[wave][fr][32 + fq * 8]);
            __builtin_amdgcn_s_setprio(1);
            #pragma unroll
            for (int d = 0; d < 4; ++d) {
                oacc[d] = __builtin_amdgcn_mfma_f32_16x16x32_bf16(pa0, vb[d][0], oacc[d], 0, 0, 0);
                oacc[d] = __builtin_amdgcn_mfma_f32_16x16x32_bf16(pa1, vb[d][1], oacc[d], 0, 0, 0);
            }
            __builtin_amdgcn_s_setprio(0);
        }

        float inv[4];
        #pragma unroll
        for (int r = 0; r < 4; ++r) {
            float v = lpart[r];
            v += __shfl_xor(v, 1);
            v += __shfl_xor(v, 2);
            v += __shfl_xor(v, 4);
            v += __shfl_xor(v, 8);
            inv[r] = 1.0f / v;
        }
        #pragma unroll
        for (int d = 0; d < 4; ++d)
            #pragma unroll
            for (int r = 0; r < 4; ++r) {
                const int qr = q0 + wave * 16 + fq * 4 + r;
                out[(size_t)(b * S + qr) * Dm + h * 64 + d * 16 + fr] = oacc[d][r] * inv[r];
            }
    }
}

// ---------------------------------------------------------------------------
extern "C" void kernel_launch(void* const* d_in, const int* in_sizes, int n_in,
                              void* d_out, int out_size, void* d_ws, size_t ws_size,
                              hipStream_t stream)
{
    const float* query = (const float*)d_in[0];
    const float* key_  = (const float*)d_in[1];
    const float* value = (const float*)d_in[2];
    const int*   amask = (const int*)d_in[3];
    const float* Wq = (const float*)d_in[4];
    const float* bq = (const float*)d_in[5];
    const float* Wk = (const float*)d_in[6];
    const float* bk = (const float*)d_in[7];
    const float* Wv = (const float*)d_in[8];
    const float* bv = (const float*)d_in[9];
    float* out = (float*)d_out;

    const size_t MD = (size_t)4096 * 1024;
    const size_t WD = (size_t)1024 * 1024;
    unsigned short* Qw  = (unsigned short*)d_ws;
    unsigned short* Kw  = Qw + MD;
    unsigned short* Vw  = Kw + MD;
    unsigned short* Vtw = Vw + MD;
    unsigned short* Xq  = Vtw + MD;
    unsigned short* Xk  = Xq + MD;
    unsigned short* Xv  = Xk + MD;
    unsigned short* Wqb = Xv + MD;
    unsigned short* Wkb = Wqb + WD;
    unsigned short* Wvb = Wkb + WD;

    hipLaunchKernelGGL(cvt6, dim3(512, 6), dim3(256), 0, stream,
                       query, key_, value, Wq, Wk, Wv,
                       Xq, Xk, Xv, Wqb, Wkb, Wvb);
    hipLaunchKernelGGL(gemm_bt, dim3(256, 3), dim3(256), 0, stream,
                       Xq, Xk, Xv, Wqb, Wkb, Wvb, bq, bk, bv, Qw, Kw, Vw);
    hipLaunchKernelGGL(vtrans, dim3(16, 16, 4), dim3(256), 0, stream, Vw, Vtw);
    hipLaunchKernelGGL(attn_fwd, dim3(8, 16, 4), dim3(256), 0, stream,
                       Qw, Kw, Vtw, amask, out);
}